// Round 11
// baseline (454.979 us; speedup 1.0000x reference)
//
#include <hip/hip_runtime.h>
#include <hip/hip_bf16.h>

// Problem constants (B=8,S=4096,D=1024, A=16, C=8, dc=64, apc=2)
#define DIM 1024
#define NANCH 16
#define NCOMP 8
#define DC 64
#define DC2 128
#define EPS_LN 1e-5f
#define EPS_NORM 1e-12f

typedef __bf16 bf16x8 __attribute__((ext_vector_type(8)));
typedef float f32x4 __attribute__((ext_vector_type(4)));

// ---- DPP rotate-reduce helpers: sum over 16-lane row, result in all lanes.
template <int CTRL>
__device__ __forceinline__ float rr_add(float v) {
  return v + __int_as_float(__builtin_amdgcn_update_dpp(
                 0, __float_as_int(v), CTRL, 0xF, 0xF, true));
}
__device__ __forceinline__ float rowsum16(float v) {
  v = rr_add<0x121>(v);  // row_ror:1
  v = rr_add<0x122>(v);  // row_ror:2
  v = rr_add<0x124>(v);  // row_ror:4
  v = rr_add<0x128>(v);  // row_ror:8
  return v;
}
// xor-32 add via v_permlane32_swap (VALU pipe) — R9-verified.
__device__ __forceinline__ float xorswap32_add(float v) {
#if __has_builtin(__builtin_amdgcn_permlane32_swap)
  typedef unsigned uv2 __attribute__((ext_vector_type(2)));
  uv2 r = __builtin_amdgcn_permlane32_swap(__float_as_uint(v),
                                           __float_as_uint(v), false, false);
  return __uint_as_float(r[0]) + __uint_as_float(r[1]);
#else
  return v + __shfl_xor(v, 32);
#endif
}
__device__ __forceinline__ float wavesum64(float v) {
  v = rowsum16(v);
  v += __shfl_xor(v, 16);
  return xorswap32_add(v);
}

// ---------------- Kernel P: fused prep (one launch) ---------------------
__global__ __launch_bounds__(256) void kprepall(
    const float* __restrict__ anchors, const float* __restrict__ Wp,
    const float* __restrict__ W2, __hip_bfloat16* __restrict__ WpT,
    __hip_bfloat16* __restrict__ W2B, __hip_bfloat16* __restrict__ AnB) {
  __shared__ float smem[64 * 65 + 16];
  int b = blockIdx.x, t = threadIdx.x;

  if (b < 16) {
    int a = b, lane = t & 63, wid = t >> 6;
    float v[4]; float ss = 0.f;
#pragma unroll
    for (int i = 0; i < 4; i++) {
      v[i] = anchors[a * DIM + t + 256 * i];
      ss += v[i] * v[i];
    }
    for (int off = 32; off; off >>= 1) ss += __shfl_down(ss, off);
    if (lane == 0) smem[4160 + wid] = ss;
    __syncthreads();
    float inv = 1.f / fmaxf(sqrtf(smem[4160] + smem[4161] + smem[4162] + smem[4163]),
                            EPS_NORM);
#pragma unroll
    for (int i = 0; i < 4; i++) smem[t + 256 * i] = v[i] * inv;
    __syncthreads();
#pragma unroll
    for (int q = 0; q < 4; q++) {
      int idx = t * 4 + q;  // 0..1023
      int ks = idx >> 5, hi = (idx >> 3) & 3, j = idx & 7;
      AnB[ks * 512 + (hi * 16 + a) * 8 + j] = __float2bfloat16(smem[idx]);
    }
  } else if (b < 144) {
    int bidx = b - 16, bj = bidx & 15, bk = bidx >> 4;
    int tx = t & 63, ty = t >> 6;
#pragma unroll
    for (int i = 0; i < 16; i++) {
      int r = ty + 4 * i;
      smem[r * 65 + tx] = Wp[(size_t)(bk * 64 + r) * DIM + bj * 64 + tx];
    }
    __syncthreads();
#pragma unroll
    for (int i = 0; i < 16; i++) {
      int r = ty + 4 * i;
      WpT[(size_t)(bj * 64 + r) * 512 + bk * 64 + tx] =
          __float2bfloat16(smem[tx * 65 + r]);
    }
  } else {
    int id = (b - 144) * 256 + t;  // [0, 65536)
    int j = id & 7, lane = (id >> 3) & 63, ks = (id >> 9) & 3,
        nt = (id >> 11) & 3, k = id >> 13;
    int e = ks * 32 + (lane >> 4) * 8 + j;
    int n = nt * 16 + (lane & 15);
    W2B[id] = __float2bfloat16(W2[k * (DC2 * DC) + e * DC + n]);
  }
}

// ---------------- Kernel 3: 8 tokens/block -> y (N x 512 bf16) ----------
// R9-exact (best measured ktoken: 85.3-86.5 us).
#define LDA_H 1032  // 1024 + 8 bf16 pad
__global__ __launch_bounds__(256, 7) void ktoken(
    const float* __restrict__ x, const __hip_bfloat16* __restrict__ AnB,
    const float* __restrict__ ln_g, const float* __restrict__ ln_b,
    const float* __restrict__ W1, const float* __restrict__ b1,
    const __hip_bfloat16* __restrict__ W2B, const float* __restrict__ b2,
    const float* __restrict__ cg, const float* __restrict__ cb,
    __hip_bfloat16* __restrict__ yout) {
  int t = threadIdx.x;
  int lane = t & 63, w = t >> 6;
  int l15 = lane & 15, quad = lane >> 4;
  int n0 = blockIdx.x * 8;

  __shared__ __hip_bfloat16 hu[8 * LDA_H];  // 16.1 KB: h, then u
  __shared__ float tri_s[8 * 16];           // 512 B
  __shared__ float part[4 * 32 * 4];        // 2 KB

  // ---- Phase A: LN + l2norm for tokens w*2, w*2+1 (one wave each) ----
  float gv[16], bv[16];
#pragma unroll
  for (int i = 0; i < 4; i++) {
    f32x4 g4 = *(const f32x4*)(&ln_g[i * 256 + lane * 4]);
    f32x4 b4 = *(const f32x4*)(&ln_b[i * 256 + lane * 4]);
#pragma unroll
    for (int j = 0; j < 4; j++) { gv[i * 4 + j] = g4[j]; bv[i * 4 + j] = b4[j]; }
  }
#pragma unroll
  for (int it = 0; it < 2; it++) {
    int tok = w * 2 + it;
    const float* xr = x + (size_t)(n0 + tok) * DIM;
    float xv[16], s = 0.f, s2 = 0.f;
#pragma unroll
    for (int i = 0; i < 4; i++) {
      f32x4 v4 = *(const f32x4*)(&xr[i * 256 + lane * 4]);
#pragma unroll
      for (int j = 0; j < 4; j++) {
        float v = v4[j];
        xv[i * 4 + j] = v; s += v; s2 += v * v;
      }
    }
    s = wavesum64(s);
    s2 = wavesum64(s2);
    float mu = s * (1.f / DIM);
    float rstd = rsqrtf(s2 * (1.f / DIM) - mu * mu + EPS_LN);
    float ss = 0.f;
#pragma unroll
    for (int i = 0; i < 16; i++) {
      float h = (xv[i] - mu) * rstd * gv[i] + bv[i];
      xv[i] = h; ss += h * h;
    }
    ss = wavesum64(ss);
    float inv = 1.f / fmaxf(sqrtf(ss), EPS_NORM);
#pragma unroll
    for (int i = 0; i < 4; i++) {
      union { uint2 u; __hip_bfloat16 h[4]; } pk;
#pragma unroll
      for (int j = 0; j < 4; j++) pk.h[j] = __float2bfloat16(xv[i * 4 + j] * inv);
      *(uint2*)(&hu[tok * LDA_H + i * 256 + lane * 4]) = pk.u;
    }
  }
  __syncthreads();

  // ---- Phase B: tri[m][a] = 1 - h@An^T, MFMA over K=1024 ----
  {
    f32x4 tacc = {0.f, 0.f, 0.f, 0.f};
    int ar = l15 & 7;  // rows 8-15 duplicate 0-7; outputs unused
#pragma unroll
    for (int ks = w * 8; ks < w * 8 + 8; ks++) {
      bf16x8 afr = *(const bf16x8*)(&hu[ar * LDA_H + ks * 32 + quad * 8]);
      bf16x8 bfr = *(const bf16x8*)(&AnB[ks * 512 + lane * 8]);
      tacc = __builtin_amdgcn_mfma_f32_16x16x32_bf16(afr, bfr, tacc, 0, 0, 0);
    }
    if (quad < 2) *(f32x4*)(&part[(w * 32 + (lane & 31)) * 4]) = tacc;
  }
  __syncthreads();
  if (t < 128) {
    int ln = t & 31, rg = t >> 5;
    float v = part[(0 * 32 + ln) * 4 + rg] + part[(1 * 32 + ln) * 4 + rg] +
              part[(2 * 32 + ln) * 4 + rg] + part[(3 * 32 + ln) * 4 + rg];
    int m = (ln >> 4) * 4 + rg, a = ln & 15;  // m in [0,8)
    tri_s[m * 16 + a] = 1.f - v;
  }
  __syncthreads();

  // ---- Phase C: u = relu(tri0*W1a + tri1*W1b + b1)^2 -> hu (bf16) ----
  {
    int k = t >> 5;
    int e0 = (t * 4) & 127;
    f32x4 w1a = *(const f32x4*)(&W1[k * 256 + e0]);
    f32x4 w1b = *(const f32x4*)(&W1[k * 256 + 128 + e0]);
    f32x4 b1v = *(const f32x4*)(&b1[k * 128 + e0]);
#pragma unroll
    for (int tok = 0; tok < 8; tok++) {
      float t0 = tri_s[tok * 16 + k], t1 = tri_s[tok * 16 + 8 + k];
      union { unsigned long long u; __hip_bfloat16 h[4]; } pk;
#pragma unroll
      for (int j = 0; j < 4; j++) {
        float uu = t0 * w1a[j] + t1 * w1b[j] + b1v[j];
        uu = fmaxf(uu, 0.f);
        pk.h[j] = __float2bfloat16(uu * uu);
      }
      *(unsigned long long*)(&hu[tok * LDA_H + t * 4]) = pk.u;
    }
  }
  __syncthreads();

  // ---- Phase D: per-comp y = u@W2 + b2, LN over dc=64, write ----
#pragma unroll
  for (int kc = 0; kc < 2; kc++) {
    int k = w * 2 + kc;
    int ar = l15 & 7;
    bf16x8 afr[4];
#pragma unroll
    for (int ks = 0; ks < 4; ks++)
      afr[ks] = *(const bf16x8*)(&hu[ar * LDA_H + k * 128 + ks * 32 + quad * 8]);
    f32x4 acc[4] = {{0,0,0,0},{0,0,0,0},{0,0,0,0},{0,0,0,0}};
#pragma unroll
    for (int nt = 0; nt < 4; nt++) {
#pragma unroll
      for (int ks = 0; ks < 4; ks++) {
        bf16x8 bfr = *(const bf16x8*)(&W2B[(size_t)(((k * 4 + nt) * 4 + ks)) * 512 + lane * 8]);
        acc[nt] = __builtin_amdgcn_mfma_f32_16x16x32_bf16(afr[ks], bfr, acc[nt], 0, 0, 0);
      }
    }
    float vals[4][4], s1[4] = {0,0,0,0}, s2[4] = {0,0,0,0};
#pragma unroll
    for (int nt = 0; nt < 4; nt++) {
      float b2v = b2[k * 64 + nt * 16 + l15];
#pragma unroll
      for (int r = 0; r < 4; r++) {
        float v = acc[nt][r] + b2v;
        vals[nt][r] = v; s1[r] += v; s2[r] += v * v;
      }
    }
#pragma unroll
    for (int r = 0; r < 4; r++) {
      s1[r] = rowsum16(s1[r]);
      s2[r] = rowsum16(s2[r]);
    }
#pragma unroll
    for (int r = 0; r < 4; r++) {
      float mu = s1[r] * (1.f / DC);
      float rs = rsqrtf(s2[r] * (1.f / DC) - mu * mu + EPS_LN);
      int tokrow = quad * 4 + r;
      if (tokrow < 8) {
#pragma unroll
        for (int nt = 0; nt < 4; nt++) {
          int d = nt * 16 + l15;
          float yn = (vals[nt][r] - mu) * rs * cg[k * 64 + d] + cb[k * 64 + d];
          yout[(size_t)(n0 + tokrow) * 512 + k * 64 + d] = __float2bfloat16(yn);
        }
      }
    }
  }
}

// ---------------- Kernel 4: out = x + sig(gate)*(y @ Wp + bp) -----------
// Round-11: LDS-FREE. A/B fragments loaded directly global->VGPR (same
// pattern ktoken Phase B/D uses with AnB/W2B): both Y and WpT are
// K-contiguous, so lane (l15,quad) reads 16 B at row tile+i*16+l15,
// k = k0+quad*8. No LDS, no barriers, no staging -> compiler pipelines
// 128 independent dwordx4 loads across the unrolled K loop. Y tile is
// read by 8 consecutive blocks (bj fast axis) -> L2/L3-hot; WpT is 1 MB
// -> L3-resident. Zero race surface.
__global__ __launch_bounds__(256, 2) void kgemm(
    const __hip_bfloat16* __restrict__ Y, const __hip_bfloat16* __restrict__ WpT,
    const float* __restrict__ x, const float* __restrict__ bp,
    const float* __restrict__ gate, float* __restrict__ out) {
  int t = threadIdx.x, lane = t & 63, wid = t >> 6;
  int bj = blockIdx.x, bm = blockIdx.y;  // bj fast axis (R9)
  int wm = (wid >> 1) * 64, wj = (wid & 1) * 64;
  int l15 = lane & 15, quad = lane >> 4;

  f32x4 acc[4][4] = {};

  const __hip_bfloat16* Yb = Y + (size_t)(bm * 128 + wm + l15) * 512 + quad * 8;
  const __hip_bfloat16* Wb = WpT + (size_t)(bj * 128 + wj + l15) * 512 + quad * 8;

#pragma unroll
  for (int k0 = 0; k0 < 512; k0 += 32) {
    bf16x8 af[4], bfr[4];
#pragma unroll
    for (int i = 0; i < 4; i++) {
      af[i]  = *(const bf16x8*)(Yb + (size_t)(i * 16) * 512 + k0);
      bfr[i] = *(const bf16x8*)(Wb + (size_t)(i * 16) * 512 + k0);
    }
#pragma unroll
    for (int i = 0; i < 4; i++)
#pragma unroll
      for (int j = 0; j < 4; j++)
        acc[i][j] = __builtin_amdgcn_mfma_f32_16x16x32_bf16(af[i], bfr[j], acc[i][j], 0, 0, 0);
  }

  float sg[4], bpv[4];
#pragma unroll
  for (int j = 0; j < 4; j++) {
    int gc = bj * 128 + wj + j * 16 + l15;
    sg[j] = 1.f / (1.f + expf(-gate[gc]));
    bpv[j] = bp[gc];
  }
#pragma unroll
  for (int i = 0; i < 4; i++) {
#pragma unroll
    for (int j = 0; j < 4; j++) {
      int gc = bj * 128 + wj + j * 16 + l15;
#pragma unroll
      for (int r = 0; r < 4; r++) {
        int gr = bm * 128 + wm + i * 16 + quad * 4 + r;
        size_t idx = (size_t)gr * DIM + gc;
        out[idx] = x[idx] + sg[j] * (acc[i][j][r] + bpv[j]);
      }
    }
  }
}

extern "C" void kernel_launch(void* const* d_in, const int* in_sizes, int n_in,
                              void* d_out, int out_size, void* d_ws, size_t ws_size,
                              hipStream_t stream) {
  const float* x       = (const float*)d_in[0];
  const float* anchors = (const float*)d_in[1];
  const float* ln_g    = (const float*)d_in[2];
  const float* ln_b    = (const float*)d_in[3];
  const float* W1      = (const float*)d_in[4];
  const float* b1      = (const float*)d_in[5];
  const float* W2      = (const float*)d_in[6];
  const float* b2      = (const float*)d_in[7];
  const float* cg      = (const float*)d_in[8];
  const float* cb      = (const float*)d_in[9];
  const float* Wp      = (const float*)d_in[10];
  const float* bp      = (const float*)d_in[11];
  const float* gate    = (const float*)d_in[12];

  int N = in_sizes[0] / DIM;  // 32768 tokens

  char* w = (char*)d_ws;
  size_t off = 0;
  __hip_bfloat16* WpT = (__hip_bfloat16*)(w + off);  off += 1 << 20;    // 1 MB
  __hip_bfloat16* W2B = (__hip_bfloat16*)(w + off);  off += 128 << 10;  // 128 KB
  __hip_bfloat16* AnB = (__hip_bfloat16*)(w + off);  off += 32 << 10;   // 32 KB
  __hip_bfloat16* Yb  = (__hip_bfloat16*)(w + off);                     // 32 MB

  kprepall<<<400, 256, 0, stream>>>(anchors, Wp, W2, WpT, W2B, AnB);
  ktoken<<<N / 8, 256, 0, stream>>>(x, AnB, ln_g, ln_b, W1, b1, W2B, b2, cg, cb, Yb);
  kgemm<<<dim3(DIM / 128, N / 128), 256, 0, stream>>>(Yb, WpT, x, bp, gate,
                                                      (float*)d_out);
}

// Round 12
// 328.132 us; speedup vs baseline: 1.3866x; 1.3866x over previous
//
#include <hip/hip_runtime.h>
#include <hip/hip_bf16.h>

// Problem constants (B=8,S=4096,D=1024, A=16, C=8, dc=64, apc=2)
#define DIM 1024
#define NANCH 16
#define NCOMP 8
#define DC 64
#define DC2 128
#define EPS_LN 1e-5f
#define EPS_NORM 1e-12f

typedef __bf16 bf16x8 __attribute__((ext_vector_type(8)));
typedef float f32x4 __attribute__((ext_vector_type(4)));

// ---- DPP rotate-reduce helpers: sum over 16-lane row, result in all lanes.
template <int CTRL>
__device__ __forceinline__ float rr_add(float v) {
  return v + __int_as_float(__builtin_amdgcn_update_dpp(
                 0, __float_as_int(v), CTRL, 0xF, 0xF, true));
}
__device__ __forceinline__ float rowsum16(float v) {
  v = rr_add<0x121>(v);  // row_ror:1
  v = rr_add<0x122>(v);  // row_ror:2
  v = rr_add<0x124>(v);  // row_ror:4
  v = rr_add<0x128>(v);  // row_ror:8
  return v;
}
// xor-32 add via v_permlane32_swap (VALU pipe) — R9-verified.
__device__ __forceinline__ float xorswap32_add(float v) {
#if __has_builtin(__builtin_amdgcn_permlane32_swap)
  typedef unsigned uv2 __attribute__((ext_vector_type(2)));
  uv2 r = __builtin_amdgcn_permlane32_swap(__float_as_uint(v),
                                           __float_as_uint(v), false, false);
  return __uint_as_float(r[0]) + __uint_as_float(r[1]);
#else
  return v + __shfl_xor(v, 32);
#endif
}
__device__ __forceinline__ float wavesum64(float v) {
  v = rowsum16(v);
  v += __shfl_xor(v, 16);
  return xorswap32_add(v);
}

// async global->LDS, 16 B per lane (dest must be wave-uniform base + lane*16)
__device__ __forceinline__ void gload16(const void* g, void* l) {
  __builtin_amdgcn_global_load_lds(
      (const __attribute__((address_space(1))) unsigned int*)g,
      (__attribute__((address_space(3))) unsigned int*)l, 16, 0, 0);
}

// ---------------- Kernel P: fused prep (one launch) ---------------------
__global__ __launch_bounds__(256) void kprepall(
    const float* __restrict__ anchors, const float* __restrict__ Wp,
    const float* __restrict__ W2, __hip_bfloat16* __restrict__ WpT,
    __hip_bfloat16* __restrict__ W2B, __hip_bfloat16* __restrict__ AnB) {
  __shared__ float smem[64 * 65 + 16];
  int b = blockIdx.x, t = threadIdx.x;

  if (b < 16) {
    int a = b, lane = t & 63, wid = t >> 6;
    float v[4]; float ss = 0.f;
#pragma unroll
    for (int i = 0; i < 4; i++) {
      v[i] = anchors[a * DIM + t + 256 * i];
      ss += v[i] * v[i];
    }
    for (int off = 32; off; off >>= 1) ss += __shfl_down(ss, off);
    if (lane == 0) smem[4160 + wid] = ss;
    __syncthreads();
    float inv = 1.f / fmaxf(sqrtf(smem[4160] + smem[4161] + smem[4162] + smem[4163]),
                            EPS_NORM);
#pragma unroll
    for (int i = 0; i < 4; i++) smem[t + 256 * i] = v[i] * inv;
    __syncthreads();
#pragma unroll
    for (int q = 0; q < 4; q++) {
      int idx = t * 4 + q;  // 0..1023
      int ks = idx >> 5, hi = (idx >> 3) & 3, j = idx & 7;
      AnB[ks * 512 + (hi * 16 + a) * 8 + j] = __float2bfloat16(smem[idx]);
    }
  } else if (b < 144) {
    int bidx = b - 16, bj = bidx & 15, bk = bidx >> 4;
    int tx = t & 63, ty = t >> 6;
#pragma unroll
    for (int i = 0; i < 16; i++) {
      int r = ty + 4 * i;
      smem[r * 65 + tx] = Wp[(size_t)(bk * 64 + r) * DIM + bj * 64 + tx];
    }
    __syncthreads();
#pragma unroll
    for (int i = 0; i < 16; i++) {
      int r = ty + 4 * i;
      WpT[(size_t)(bj * 64 + r) * 512 + bk * 64 + tx] =
          __float2bfloat16(smem[tx * 65 + r]);
    }
  } else {
    int id = (b - 144) * 256 + t;  // [0, 65536)
    int j = id & 7, lane = (id >> 3) & 63, ks = (id >> 9) & 3,
        nt = (id >> 11) & 3, k = id >> 13;
    int e = ks * 32 + (lane >> 4) * 8 + j;
    int n = nt * 16 + (lane & 15);
    W2B[id] = __float2bfloat16(W2[k * (DC2 * DC) + e * DC + n]);
  }
}

// ---------------- Kernel 3: 8 tokens/block -> y (N x 512 bf16) ----------
// R9-exact (best measured ktoken: 85.3-86.5 us).
#define LDA_H 1032  // 1024 + 8 bf16 pad
__global__ __launch_bounds__(256, 7) void ktoken(
    const float* __restrict__ x, const __hip_bfloat16* __restrict__ AnB,
    const float* __restrict__ ln_g, const float* __restrict__ ln_b,
    const float* __restrict__ W1, const float* __restrict__ b1,
    const __hip_bfloat16* __restrict__ W2B, const float* __restrict__ b2,
    const float* __restrict__ cg, const float* __restrict__ cb,
    __hip_bfloat16* __restrict__ yout) {
  int t = threadIdx.x;
  int lane = t & 63, w = t >> 6;
  int l15 = lane & 15, quad = lane >> 4;
  int n0 = blockIdx.x * 8;

  __shared__ __hip_bfloat16 hu[8 * LDA_H];  // 16.1 KB: h, then u
  __shared__ float tri_s[8 * 16];           // 512 B
  __shared__ float part[4 * 32 * 4];        // 2 KB

  // ---- Phase A: LN + l2norm for tokens w*2, w*2+1 (one wave each) ----
  float gv[16], bv[16];
#pragma unroll
  for (int i = 0; i < 4; i++) {
    f32x4 g4 = *(const f32x4*)(&ln_g[i * 256 + lane * 4]);
    f32x4 b4 = *(const f32x4*)(&ln_b[i * 256 + lane * 4]);
#pragma unroll
    for (int j = 0; j < 4; j++) { gv[i * 4 + j] = g4[j]; bv[i * 4 + j] = b4[j]; }
  }
#pragma unroll
  for (int it = 0; it < 2; it++) {
    int tok = w * 2 + it;
    const float* xr = x + (size_t)(n0 + tok) * DIM;
    float xv[16], s = 0.f, s2 = 0.f;
#pragma unroll
    for (int i = 0; i < 4; i++) {
      f32x4 v4 = *(const f32x4*)(&xr[i * 256 + lane * 4]);
#pragma unroll
      for (int j = 0; j < 4; j++) {
        float v = v4[j];
        xv[i * 4 + j] = v; s += v; s2 += v * v;
      }
    }
    s = wavesum64(s);
    s2 = wavesum64(s2);
    float mu = s * (1.f / DIM);
    float rstd = rsqrtf(s2 * (1.f / DIM) - mu * mu + EPS_LN);
    float ss = 0.f;
#pragma unroll
    for (int i = 0; i < 16; i++) {
      float h = (xv[i] - mu) * rstd * gv[i] + bv[i];
      xv[i] = h; ss += h * h;
    }
    ss = wavesum64(ss);
    float inv = 1.f / fmaxf(sqrtf(ss), EPS_NORM);
#pragma unroll
    for (int i = 0; i < 4; i++) {
      union { uint2 u; __hip_bfloat16 h[4]; } pk;
#pragma unroll
      for (int j = 0; j < 4; j++) pk.h[j] = __float2bfloat16(xv[i * 4 + j] * inv);
      *(uint2*)(&hu[tok * LDA_H + i * 256 + lane * 4]) = pk.u;
    }
  }
  __syncthreads();

  // ---- Phase B: tri[m][a] = 1 - h@An^T, MFMA over K=1024 ----
  {
    f32x4 tacc = {0.f, 0.f, 0.f, 0.f};
    int ar = l15 & 7;  // rows 8-15 duplicate 0-7; outputs unused
#pragma unroll
    for (int ks = w * 8; ks < w * 8 + 8; ks++) {
      bf16x8 afr = *(const bf16x8*)(&hu[ar * LDA_H + ks * 32 + quad * 8]);
      bf16x8 bfr = *(const bf16x8*)(&AnB[ks * 512 + lane * 8]);
      tacc = __builtin_amdgcn_mfma_f32_16x16x32_bf16(afr, bfr, tacc, 0, 0, 0);
    }
    if (quad < 2) *(f32x4*)(&part[(w * 32 + (lane & 31)) * 4]) = tacc;
  }
  __syncthreads();
  if (t < 128) {
    int ln = t & 31, rg = t >> 5;
    float v = part[(0 * 32 + ln) * 4 + rg] + part[(1 * 32 + ln) * 4 + rg] +
              part[(2 * 32 + ln) * 4 + rg] + part[(3 * 32 + ln) * 4 + rg];
    int m = (ln >> 4) * 4 + rg, a = ln & 15;  // m in [0,8)
    tri_s[m * 16 + a] = 1.f - v;
  }
  __syncthreads();

  // ---- Phase C: u = relu(tri0*W1a + tri1*W1b + b1)^2 -> hu (bf16) ----
  {
    int k = t >> 5;
    int e0 = (t * 4) & 127;
    f32x4 w1a = *(const f32x4*)(&W1[k * 256 + e0]);
    f32x4 w1b = *(const f32x4*)(&W1[k * 256 + 128 + e0]);
    f32x4 b1v = *(const f32x4*)(&b1[k * 128 + e0]);
#pragma unroll
    for (int tok = 0; tok < 8; tok++) {
      float t0 = tri_s[tok * 16 + k], t1 = tri_s[tok * 16 + 8 + k];
      union { unsigned long long u; __hip_bfloat16 h[4]; } pk;
#pragma unroll
      for (int j = 0; j < 4; j++) {
        float uu = t0 * w1a[j] + t1 * w1b[j] + b1v[j];
        uu = fmaxf(uu, 0.f);
        pk.h[j] = __float2bfloat16(uu * uu);
      }
      *(unsigned long long*)(&hu[tok * LDA_H + t * 4]) = pk.u;
    }
  }
  __syncthreads();

  // ---- Phase D: per-comp y = u@W2 + b2, LN over dc=64, write ----
#pragma unroll
  for (int kc = 0; kc < 2; kc++) {
    int k = w * 2 + kc;
    int ar = l15 & 7;
    bf16x8 afr[4];
#pragma unroll
    for (int ks = 0; ks < 4; ks++)
      afr[ks] = *(const bf16x8*)(&hu[ar * LDA_H + k * 128 + ks * 32 + quad * 8]);
    f32x4 acc[4] = {{0,0,0,0},{0,0,0,0},{0,0,0,0},{0,0,0,0}};
#pragma unroll
    for (int nt = 0; nt < 4; nt++) {
#pragma unroll
      for (int ks = 0; ks < 4; ks++) {
        bf16x8 bfr = *(const bf16x8*)(&W2B[(size_t)(((k * 4 + nt) * 4 + ks)) * 512 + lane * 8]);
        acc[nt] = __builtin_amdgcn_mfma_f32_16x16x32_bf16(afr[ks], bfr, acc[nt], 0, 0, 0);
      }
    }
    float vals[4][4], s1[4] = {0,0,0,0}, s2[4] = {0,0,0,0};
#pragma unroll
    for (int nt = 0; nt < 4; nt++) {
      float b2v = b2[k * 64 + nt * 16 + l15];
#pragma unroll
      for (int r = 0; r < 4; r++) {
        float v = acc[nt][r] + b2v;
        vals[nt][r] = v; s1[r] += v; s2[r] += v * v;
      }
    }
#pragma unroll
    for (int r = 0; r < 4; r++) {
      s1[r] = rowsum16(s1[r]);
      s2[r] = rowsum16(s2[r]);
    }
#pragma unroll
    for (int r = 0; r < 4; r++) {
      float mu = s1[r] * (1.f / DC);
      float rs = rsqrtf(s2[r] * (1.f / DC) - mu * mu + EPS_LN);
      int tokrow = quad * 4 + r;
      if (tokrow < 8) {
#pragma unroll
        for (int nt = 0; nt < 4; nt++) {
          int d = nt * 16 + l15;
          float yn = (vals[nt][r] - mu) * rs * cg[k * 64 + d] + cb[k * 64 + d];
          yout[(size_t)(n0 + tokrow) * 512 + k * 64 + d] = __float2bfloat16(yn);
        }
      }
    }
  }
}

// ---------------- Kernel 4: out = x + sig(gate)*(y @ Wp + bp) -----------
// R9 structure (staged, single-buffered, XOR swizzle) + Round-12 change:
// XCD-aware block remap (T1). Without it, the 8 bj-blocks sharing one
// Y-tile dispatch consecutively but round-robin across 8 XCDs — each XCD
// refetches the same tile into its private L2. Remap gives XCD x the bm
// range [32x, 32x+32) with all bj consecutive -> Y-tile reuse is L2-local,
// WpT (1 MB) L2-resident per XCD. Bijective: 2048 %% 8 == 0.
__global__ __launch_bounds__(256, 4) void kgemm(
    const __hip_bfloat16* __restrict__ Y, const __hip_bfloat16* __restrict__ WpT,
    const float* __restrict__ x, const float* __restrict__ bp,
    const float* __restrict__ gate, float* __restrict__ out) {
  __shared__ alignas(16) __hip_bfloat16 As[128 * 64];
  __shared__ alignas(16) __hip_bfloat16 Bs[128 * 64];
  int t = threadIdx.x, lane = t & 63, wid = t >> 6;
  // XCD-aware remap: lid in dispatch order (x fastest), xcd = lid%8.
  int lid = blockIdx.x + 8 * blockIdx.y;          // 0..2047
  int wrk = (lid & 7) * 256 + (lid >> 3);         // XCD-grouped work id
  int bj = wrk & 7, bm = wrk >> 3;
  int wm = (wid >> 1) * 64, wj = (wid & 1) * 64;
  int l15 = lane & 15, quad = lane >> 4;

  f32x4 acc[4][4] = {};

  int srow[4], scol[4];
#pragma unroll
  for (int it = 0; it < 4; it++) {
    int byteo = it * 4096 + t * 16;
    int row = byteo >> 7, colb = byteo & 127;
    srow[it] = row;
    scol[it] = (colb ^ ((row & 7) << 4)) >> 1;
  }

  for (int kt = 0; kt < 8; kt++) {
    int k0 = kt * 64;
#pragma unroll
    for (int it = 0; it < 4; it++) {
      gload16(Y + (size_t)(bm * 128 + srow[it]) * 512 + k0 + scol[it],
              As + (it * 4096 + t * 16) / 2);
      gload16(WpT + (size_t)(bj * 128 + srow[it]) * 512 + k0 + scol[it],
              Bs + (it * 4096 + t * 16) / 2);
    }
    __syncthreads();
#pragma unroll
    for (int kk = 0; kk < 64; kk += 32) {
      bf16x8 af[4], bfr[4];
#pragma unroll
      for (int i = 0; i < 4; i++) {
        int ra = wm + i * 16 + l15, rb = wj + i * 16 + l15;
        int cb2 = (kk + quad * 8) * 2;
        af[i]  = *(const bf16x8*)((const char*)As + ra * 128 + (cb2 ^ ((ra & 7) << 4)));
        bfr[i] = *(const bf16x8*)((const char*)Bs + rb * 128 + (cb2 ^ ((rb & 7) << 4)));
      }
#pragma unroll
      for (int i = 0; i < 4; i++)
#pragma unroll
        for (int j = 0; j < 4; j++)
          acc[i][j] = __builtin_amdgcn_mfma_f32_16x16x32_bf16(af[i], bfr[j], acc[i][j], 0, 0, 0);
    }
    __syncthreads();
  }

  float sg[4], bpv[4];
#pragma unroll
  for (int j = 0; j < 4; j++) {
    int gc = bj * 128 + wj + j * 16 + l15;
    sg[j] = 1.f / (1.f + expf(-gate[gc]));
    bpv[j] = bp[gc];
  }
#pragma unroll
  for (int i = 0; i < 4; i++) {
#pragma unroll
    for (int j = 0; j < 4; j++) {
      int gc = bj * 128 + wj + j * 16 + l15;
#pragma unroll
      for (int r = 0; r < 4; r++) {
        int gr = bm * 128 + wm + i * 16 + quad * 4 + r;
        size_t idx = (size_t)gr * DIM + gc;
        out[idx] = x[idx] + sg[j] * (acc[i][j][r] + bpv[j]);
      }
    }
  }
}

extern "C" void kernel_launch(void* const* d_in, const int* in_sizes, int n_in,
                              void* d_out, int out_size, void* d_ws, size_t ws_size,
                              hipStream_t stream) {
  const float* x       = (const float*)d_in[0];
  const float* anchors = (const float*)d_in[1];
  const float* ln_g    = (const float*)d_in[2];
  const float* ln_b    = (const float*)d_in[3];
  const float* W1      = (const float*)d_in[4];
  const float* b1      = (const float*)d_in[5];
  const float* W2      = (const float*)d_in[6];
  const float* b2      = (const float*)d_in[7];
  const float* cg      = (const float*)d_in[8];
  const float* cb      = (const float*)d_in[9];
  const float* Wp      = (const float*)d_in[10];
  const float* bp      = (const float*)d_in[11];
  const float* gate    = (const float*)d_in[12];

  int N = in_sizes[0] / DIM;  // 32768 tokens

  char* w = (char*)d_ws;
  size_t off = 0;
  __hip_bfloat16* WpT = (__hip_bfloat16*)(w + off);  off += 1 << 20;    // 1 MB
  __hip_bfloat16* W2B = (__hip_bfloat16*)(w + off);  off += 128 << 10;  // 128 KB
  __hip_bfloat16* AnB = (__hip_bfloat16*)(w + off);  off += 32 << 10;   // 32 KB
  __hip_bfloat16* Yb  = (__hip_bfloat16*)(w + off);                     // 32 MB

  kprepall<<<400, 256, 0, stream>>>(anchors, Wp, W2, WpT, W2B, AnB);
  ktoken<<<N / 8, 256, 0, stream>>>(x, AnB, ln_g, ln_b, W1, b1, W2B, b2, cg, cb, Yb);
  kgemm<<<dim3(8, N / 128), 256, 0, stream>>>(Yb, WpT, x, bp, gate,
                                              (float*)d_out);
}